// Round 4
// baseline (4772.488 us; speedup 1.0000x reference)
//
#include <hip/hip_runtime.h>
#include <math.h>

// Conv1D(k=2,F=64,relu) -> LSTM1(H=100, relu cell, seq) -> LSTM2 (last) ->
// Dense(3) -> softmax.  B=128, T=2048, T'=2047.
//
// Round-4 design:
//  * 256 thr/block, __launch_bounds__(256,1): arch-VGPR need ~240 < 256 cap
//    (rounds 2/3 at (512,2) forced weights into AGPRs: VGPR_Count=104/116).
//  * K-split lane pairs: thread pair p owns gates {i,f,g,o} of hidden unit p;
//    even lane dots K-half 0, odd lane K-half 1; one ds_swizzle(xor1) per
//    gate combines.  Halves per-lane LDS broadcast traffic (the round-3
//    bottleneck: 204KB/CU/step -> 51KB) AND makes the cell update lane-local
//    (no gate exchange): ONE barrier per step, parity double-buffered slots.
//  * Threads 200..255 do conv (producer) / h1-row prefetch (consumer),
//    overlapped with the dot work of threads 0..199.
//  * Same producer/consumer block split + agent-scope progress handshake.

typedef _Float16 h2 __attribute__((ext_vector_type(2)));

#define BB 128
#define TT 2048
#define TP 2047
#define HH 100
#define G4 400
#define FF 64
#define CH 16

#define L44(X) X(0) X(1) X(2) X(3) X(4) X(5) X(6) X(7) X(8) X(9) \
 X(10) X(11) X(12) X(13) X(14) X(15) X(16) X(17) X(18) X(19) \
 X(20) X(21) X(22) X(23) X(24) X(25) X(26) X(27) X(28) X(29) \
 X(30) X(31) X(32) X(33) X(34) X(35) X(36) X(37) X(38) X(39) \
 X(40) X(41) X(42) X(43)
#define L50(X) L44(X) X(44) X(45) X(46) X(47) X(48) X(49)

#define DW(q) h2 wa##q, wb##q, wc##q, wd##q;

// producer combined column: K = [conv-x(64) ; U(100) ; pad(12)]
static __device__ __forceinline__ _Float16 pw(const float* __restrict__ W,
                                              const float* __restrict__ U,
                                              int c, int k) {
    float v = (k < FF) ? W[k * G4 + c] : (k < FF + HH ? U[(k - FF) * G4 + c] : 0.0f);
    return (_Float16)v;
}
// consumer combined column: K = [W(100) ; U(100)]
static __device__ __forceinline__ _Float16 cw(const float* __restrict__ W,
                                              const float* __restrict__ U,
                                              int c, int k) {
    float v = (k < HH) ? W[k * G4 + c] : U[(k - HH) * G4 + c];
    return (_Float16)v;
}

#define LWP(q) { const int k = kb + 2 * (q); \
  wa##q = h2{pw(W,U,cA,k), pw(W,U,cA,k+1)}; \
  wb##q = h2{pw(W,U,cB,k), pw(W,U,cB,k+1)}; \
  wc##q = h2{pw(W,U,cC,k), pw(W,U,cC,k+1)}; \
  wd##q = h2{pw(W,U,cD,k), pw(W,U,cD,k+1)}; }
#define LWC(q) { const int k = kb + 2 * (q); \
  wa##q = h2{cw(W,U,cA,k), cw(W,U,cA,k+1)}; \
  wb##q = h2{cw(W,U,cB,k), cw(W,U,cB,k+1)}; \
  wc##q = h2{cw(W,U,cC,k), cw(W,U,cC,k+1)}; \
  wd##q = h2{cw(W,U,cD,k), cw(W,U,cD,k+1)}; }

#define FD(w, x, acc) acc = __builtin_amdgcn_fdot2(w, x, acc, false)
#define B2(f) __builtin_bit_cast(h2, f)

#define DOT4(r, q0, q1, q2, q3) { const float4 v = vb[r]; \
  const h2 x0 = B2(v.x), x1 = B2(v.y), x2 = B2(v.z), x3 = B2(v.w); \
  FD(wa##q0, x0, zA0); FD(wb##q0, x0, zB0); FD(wc##q0, x0, zC0); FD(wd##q0, x0, zD0); \
  FD(wa##q1, x1, zA1); FD(wb##q1, x1, zB1); FD(wc##q1, x1, zC1); FD(wd##q1, x1, zD1); \
  FD(wa##q2, x2, zA0); FD(wb##q2, x2, zB0); FD(wc##q2, x2, zC0); FD(wd##q2, x2, zD0); \
  FD(wa##q3, x3, zA1); FD(wb##q3, x3, zB1); FD(wc##q3, x3, zC1); FD(wd##q3, x3, zD1); }

#define DOTT(q0, q1) { const float2 v = *tb; \
  const h2 x0 = B2(v.x), x1 = B2(v.y); \
  FD(wa##q0, x0, zA0); FD(wb##q0, x0, zB0); FD(wc##q0, x0, zC0); FD(wd##q0, x0, zD0); \
  FD(wa##q1, x1, zA1); FD(wb##q1, x1, zB1); FD(wc##q1, x1, zC1); FD(wd##q1, x1, zD1); }

// sum over the lane pair (xor 1 within 32-lane group; pairs never cross it)
static __device__ __forceinline__ float pairsum(float z) {
    int s = __builtin_amdgcn_ds_swizzle(__builtin_bit_cast(int, z), 0x041F);
    return z + __builtin_bit_cast(float, s);
}
static __device__ __forceinline__ float sig(float z) {
    return 1.0f / (1.0f + __expf(-z));
}

__global__ __launch_bounds__(256, 1)
void fused_lstm_kernel(const float* __restrict__ s,       // [B,T]
                       const float* __restrict__ conv_w,  // [2,1,F]
                       const float* __restrict__ conv_b,  // [F]
                       const float* __restrict__ w1, const float* __restrict__ u1,
                       const float* __restrict__ b1,
                       const float* __restrict__ w2, const float* __restrict__ u2,
                       const float* __restrict__ b2,
                       const float* __restrict__ dw, const float* __restrict__ db,
                       _Float16* __restrict__ h1,         // [TP,B,H] in d_ws
                       int* __restrict__ prog,            // [B] in d_ws
                       float* __restrict__ out)           // [B,3]
{
    const int tid = threadIdx.x;

    __shared__ float s_buf[TT];                     // producer only (8 KB)
    __shared__ __align__(16) _Float16 xh[2 * 208];  // parity slots

    const int p  = (tid < 200) ? (tid >> 1) : 0;
    const int cA = p, cB = HH + p, cC = 2 * HH + p, cD = 3 * HH + p;
    const int odd = tid & 1;

    if (blockIdx.x < BB) {
        // ================= PRODUCER: conv + LSTM1 =================
        const int b = blockIdx.x;
        const float* W = w1;
        const float* U = u1;
        const int ST = 176;                 // slot: [x(64); h(100); pad(12)]
        const int kb   = odd ? 88 : 0;      // K-half base
        const int xoff = odd ? 88 : 0;      // LDS half-offset (bytes 176: 16-aligned)

        L44(DW)
        L44(LWP)
        const float biA = b1[cA], biB = b1[cB], biC = b1[cC], biD = b1[cD];

        float cv0 = 0.f, cv1 = 0.f, cb0 = 0.f, cv0b = 0.f, cv1b = 0.f, cb0b = 0.f;
        const int f1 = tid - 200;
        if (tid >= 200) {
            cv0 = conv_w[f1]; cv1 = conv_w[FF + f1]; cb0 = conv_b[f1];
            if (f1 < 8) { cv0b = conv_w[56 + f1]; cv1b = conv_w[FF + 56 + f1]; cb0b = conv_b[56 + f1]; }
        }

        for (int i = tid; i < TT; i += 256) s_buf[i] = s[(size_t)b * TT + i];
        for (int i = tid; i < 2 * ST; i += 256) xh[i] = (_Float16)0.0f;
        __syncthreads();
        if (tid >= 200) {                   // x(0) into slot 0
            xh[f1] = (_Float16)fmaxf(fmaf(s_buf[0], cv0, fmaf(s_buf[1], cv1, cb0)), 0.f);
            if (f1 < 8)
                xh[56 + f1] = (_Float16)fmaxf(fmaf(s_buf[0], cv0b, fmaf(s_buf[1], cv1b, cb0b)), 0.f);
        }
        __syncthreads();

        float c = 0.0f;
        for (int t = 0; t < TP; ++t) {
            _Float16* cur = xh + (t & 1) * ST;
            _Float16* nxt = xh + ((t & 1) ^ 1) * ST;
            if (tid < 200) {
                float zA0 = 0.f, zA1 = 0.f, zB0 = 0.f, zB1 = 0.f;
                float zC0 = 0.f, zC1 = 0.f, zD0 = 0.f, zD1 = 0.f;
                const float4* vb = (const float4*)(cur + xoff);
                DOT4(0,0,1,2,3)     DOT4(1,4,5,6,7)     DOT4(2,8,9,10,11)
                DOT4(3,12,13,14,15) DOT4(4,16,17,18,19) DOT4(5,20,21,22,23)
                DOT4(6,24,25,26,27) DOT4(7,28,29,30,31) DOT4(8,32,33,34,35)
                DOT4(9,36,37,38,39) DOT4(10,40,41,42,43)
                const float zi = pairsum(zA0 + zA1) + biA;
                const float zf = pairsum(zB0 + zB1) + biB;
                const float zg = pairsum(zC0 + zC1) + biC;
                const float zo = pairsum(zD0 + zD1) + biD;
                const float gi = sig(zi), gf = sig(zf), go = sig(zo);
                const float gg = fmaxf(zg, 0.f);
                c = fmaf(gf, c, gi * gg);
                const float h = go * fmaxf(c, 0.f);
                if (odd) {
                    const _Float16 hq = (_Float16)h;
                    nxt[FF + p] = hq;
                    h1[((size_t)t * BB + b) * HH + p] = hq;
                }
            } else if (t + 1 < TP) {        // conv x(t+1) into next slot
                nxt[f1] = (_Float16)fmaxf(fmaf(s_buf[t + 1], cv0, fmaf(s_buf[t + 2], cv1, cb0)), 0.f);
                if (f1 < 8)
                    nxt[56 + f1] = (_Float16)fmaxf(fmaf(s_buf[t + 1], cv0b, fmaf(s_buf[t + 2], cv1b, cb0b)), 0.f);
            }
            const bool pub = (((t + 1) & 7) == 0) || (t + 1) == TP;
            if (pub) __threadfence();
            __syncthreads();
            if (pub && tid == 0)
                __hip_atomic_store(&prog[b], t + 1, __ATOMIC_RELEASE,
                                   __HIP_MEMORY_SCOPE_AGENT);
        }
    } else {
        // ================= CONSUMER: LSTM2 + dense + softmax =================
        const int b = blockIdx.x - BB;
        const float* W = w2;
        const float* U = u2;
        const int ST = 208;                 // slot: [x(100); pad(4); h(100); pad(4)]
        const int kb   = odd ? 100 : 0;
        const int xoff = odd ? 104 : 0;     // bytes 208: 16-aligned

        L50(DW)
        L50(LWC)
        const float biA = b2[cA], biB = b2[cB], biC = b2[cC], biD = b2[cD];

        for (int i = tid; i < 2 * ST; i += 256) xh[i] = (_Float16)0.0f;

        float c = 0.0f;
        int t = 0;
        const int NCH = (TP + CH - 1) / CH;
        for (int cc = 0; cc < NCH; ++cc) {
            const int tend = (CH * (cc + 1) < TP) ? CH * (cc + 1) : TP;
            const int need = (tend + 1 < TP) ? tend + 1 : TP;
            if (tid == 0) {
                while (__hip_atomic_load(&prog[b], __ATOMIC_ACQUIRE,
                                         __HIP_MEMORY_SCOPE_AGENT) < need)
                    __builtin_amdgcn_s_sleep(2);
            }
            __syncthreads();
            if (cc == 0) {                  // x(0) = h1 row 0 into slot 0
                if (tid >= 200 && tid < 225) {
                    const int j = tid - 200;
                    const _Float16* src = h1 + (size_t)b * HH;
                    *(float2*)(xh + 4 * j) = *(const float2*)(src + 4 * j);
                }
                __syncthreads();
            }
            for (; t < tend; ++t) {
                _Float16* cur = xh + (t & 1) * ST;
                _Float16* nxt = xh + ((t & 1) ^ 1) * ST;
                if (tid < 200) {
                    float zA0 = 0.f, zA1 = 0.f, zB0 = 0.f, zB1 = 0.f;
                    float zC0 = 0.f, zC1 = 0.f, zD0 = 0.f, zD1 = 0.f;
                    const float4* vb = (const float4*)(cur + xoff);
                    DOT4(0,0,1,2,3)     DOT4(1,4,5,6,7)     DOT4(2,8,9,10,11)
                    DOT4(3,12,13,14,15) DOT4(4,16,17,18,19) DOT4(5,20,21,22,23)
                    DOT4(6,24,25,26,27) DOT4(7,28,29,30,31) DOT4(8,32,33,34,35)
                    DOT4(9,36,37,38,39) DOT4(10,40,41,42,43) DOT4(11,44,45,46,47)
                    const float2* tb = (const float2*)(cur + xoff + 96);
                    DOTT(48, 49)
                    const float zi = pairsum(zA0 + zA1) + biA;
                    const float zf = pairsum(zB0 + zB1) + biB;
                    const float zg = pairsum(zC0 + zC1) + biC;
                    const float zo = pairsum(zD0 + zD1) + biD;
                    const float gi = sig(zi), gf = sig(zf), go = sig(zo);
                    const float gg = fmaxf(zg, 0.f);
                    c = fmaf(gf, c, gi * gg);
                    const float h = go * fmaxf(c, 0.f);
                    if (odd) nxt[104 + p] = (_Float16)h;
                } else if (tid < 225 && t + 1 < TP) {   // prefetch h1 row t+1
                    const int j = tid - 200;
                    const _Float16* src = h1 + ((size_t)(t + 1) * BB + b) * HH;
                    *(float2*)(nxt + 4 * j) = *(const float2*)(src + 4 * j);
                }
                __syncthreads();
            }
        }

        if (tid == 0) {                     // final h2 lives in slot 1 h-region
            float l[3];
#pragma unroll
            for (int a = 0; a < 3; ++a) {
                float acc = db[a];
                for (int j = 0; j < HH; ++j)
                    acc = fmaf((float)xh[208 + 104 + j], dw[j * 3 + a], acc);
                l[a] = acc;
            }
            const float m = fmaxf(l[0], fmaxf(l[1], l[2]));
            const float e0 = __expf(l[0] - m), e1 = __expf(l[1] - m), e2 = __expf(l[2] - m);
            const float inv = 1.0f / (e0 + e1 + e2);
            out[b * 3 + 0] = e0 * inv;
            out[b * 3 + 1] = e1 * inv;
            out[b * 3 + 2] = e2 * inv;
        }
    }
}

// ---------------- launch ----------------------------------------------------
extern "C" void kernel_launch(void* const* d_in, const int* in_sizes, int n_in,
                              void* d_out, int out_size, void* d_ws, size_t ws_size,
                              hipStream_t stream) {
    const float* s      = (const float*)d_in[0];
    const float* conv_w = (const float*)d_in[1];
    const float* conv_b = (const float*)d_in[2];
    const float* w1     = (const float*)d_in[3];
    const float* u1     = (const float*)d_in[4];
    const float* b1     = (const float*)d_in[5];
    const float* w2     = (const float*)d_in[6];
    const float* u2     = (const float*)d_in[7];
    const float* b2     = (const float*)d_in[8];
    const float* dw     = (const float*)d_in[9];
    const float* db     = (const float*)d_in[10];

    int* prog    = (int*)d_ws;                        // [128] flags (poison<0)
    _Float16* h1 = (_Float16*)((char*)d_ws + 512);    // [TP,B,H] f16, 52.4 MB

    fused_lstm_kernel<<<2 * BB, 256, 0, stream>>>(
        s, conv_w, conv_b, w1, u1, b1, w2, u2, b2, dw, db, h1, prog, (float*)d_out);
}

// Round 5
// 2477.822 us; speedup vs baseline: 1.9261x; 1.9261x over previous
//
#include <hip/hip_runtime.h>
#include <math.h>

// Conv1D(k=2,F=64,relu) -> LSTM1(H=100, relu cell, seq) -> LSTM2 (last) ->
// Dense(3) -> softmax.  B=128, T=2048, T'=2047.
//
// Round-5 design:
//  * ONE block per batch element (128 blocks x 512 threads): waves 0..3 run
//    conv+LSTM1 (producer), waves 4..7 run LSTM2 one step behind (consumer).
//    h1 flows through a 2-slot LDS ring -- NO global staging, NO atomics,
//    NO threadfence, NO polling (round 4's cross-XCD h1 round trip + 1
//    wave/SIMD occupancy was an 82%-stall regression).  One barrier/step;
//    both role paths execute identical barrier counts (wave-specialized).
//  * Each SIMD hosts 1 producer + 1 consumer wave (2 waves/SIMD) -> the two
//    roles hide each other's LDS/VALU latency.
//  * Round-4 lane-pair K-split retained: thread pair p owns gates {i,f,g,o}
//    of unit p; even lane dots K-half 0, odd lane K-half 1; ds_swizzle xor-1
//    combines.  Weights in named h2 (2xf16) regs; launch_bounds(512,2) caps
//    at 256 VGPRs (need ~230 -> arch-resident, no AGPR demotion).

typedef _Float16 h2 __attribute__((ext_vector_type(2)));

#define BB 128
#define TT 2048
#define TP 2047
#define HH 100
#define G4 400
#define FF 64

#define L44(X) X(0) X(1) X(2) X(3) X(4) X(5) X(6) X(7) X(8) X(9) \
 X(10) X(11) X(12) X(13) X(14) X(15) X(16) X(17) X(18) X(19) \
 X(20) X(21) X(22) X(23) X(24) X(25) X(26) X(27) X(28) X(29) \
 X(30) X(31) X(32) X(33) X(34) X(35) X(36) X(37) X(38) X(39) \
 X(40) X(41) X(42) X(43)
#define L50(X) L44(X) X(44) X(45) X(46) X(47) X(48) X(49)

#define DW(q) h2 wa##q, wb##q, wc##q, wd##q;

// producer combined column: K = [conv-x(64) ; U(100) ; pad(12)] -> 176
static __device__ __forceinline__ _Float16 pw(const float* __restrict__ W,
                                              const float* __restrict__ U,
                                              int c, int k) {
    float v = (k < FF) ? W[k * G4 + c] : (k < FF + HH ? U[(k - FF) * G4 + c] : 0.0f);
    return (_Float16)v;
}
// consumer combined column: K = [W(100) ; gap(4) ; U(100) ; pad(4)] -> 208
// (even lane queries k in [0,100), odd lane k in [104,204))
static __device__ __forceinline__ _Float16 cwf(const float* __restrict__ W,
                                               const float* __restrict__ U,
                                               int c, int k) {
    float v = (k < HH) ? W[k * G4 + c] : U[(k - 104) * G4 + c];
    return (_Float16)v;
}

#define LWP(q) { const int k = kb + 2 * (q); \
  wa##q = h2{pw(W,U,cA,k), pw(W,U,cA,k+1)}; \
  wb##q = h2{pw(W,U,cB,k), pw(W,U,cB,k+1)}; \
  wc##q = h2{pw(W,U,cC,k), pw(W,U,cC,k+1)}; \
  wd##q = h2{pw(W,U,cD,k), pw(W,U,cD,k+1)}; }
#define LWC(q) { const int k = kb + 2 * (q); \
  wa##q = h2{cwf(W,U,cA,k), cwf(W,U,cA,k+1)}; \
  wb##q = h2{cwf(W,U,cB,k), cwf(W,U,cB,k+1)}; \
  wc##q = h2{cwf(W,U,cC,k), cwf(W,U,cC,k+1)}; \
  wd##q = h2{cwf(W,U,cD,k), cwf(W,U,cD,k+1)}; }

#define FD(w, x, acc) acc = __builtin_amdgcn_fdot2(w, x, acc, false)
#define B2(f) __builtin_bit_cast(h2, f)

#define DOT4(r, q0, q1, q2, q3) { const float4 v = vb[r]; \
  const h2 x0 = B2(v.x), x1 = B2(v.y), x2 = B2(v.z), x3 = B2(v.w); \
  FD(wa##q0, x0, zA0); FD(wb##q0, x0, zB0); FD(wc##q0, x0, zC0); FD(wd##q0, x0, zD0); \
  FD(wa##q1, x1, zA1); FD(wb##q1, x1, zB1); FD(wc##q1, x1, zC1); FD(wd##q1, x1, zD1); \
  FD(wa##q2, x2, zA0); FD(wb##q2, x2, zB0); FD(wc##q2, x2, zC0); FD(wd##q2, x2, zD0); \
  FD(wa##q3, x3, zA1); FD(wb##q3, x3, zB1); FD(wc##q3, x3, zC1); FD(wd##q3, x3, zD1); }

#define DOTT(q0, q1) { const float2 v = *tb; \
  const h2 x0 = B2(v.x), x1 = B2(v.y); \
  FD(wa##q0, x0, zA0); FD(wb##q0, x0, zB0); FD(wc##q0, x0, zC0); FD(wd##q0, x0, zD0); \
  FD(wa##q1, x1, zA1); FD(wb##q1, x1, zB1); FD(wc##q1, x1, zC1); FD(wd##q1, x1, zD1); }

// sum over the lane pair (xor-1 swizzle; pairs never straddle a 32-lane group)
static __device__ __forceinline__ float pairsum(float z) {
    int sx = __builtin_amdgcn_ds_swizzle(__builtin_bit_cast(int, z), 0x041F);
    return z + __builtin_bit_cast(float, sx);
}
static __device__ __forceinline__ float sig(float z) {
    return 1.0f / (1.0f + __expf(-z));
}

__global__ __launch_bounds__(512, 2)
void fused_lstm_kernel(const float* __restrict__ s,       // [B,T]
                       const float* __restrict__ conv_w,  // [2,1,F]
                       const float* __restrict__ conv_b,  // [F]
                       const float* __restrict__ w1, const float* __restrict__ u1,
                       const float* __restrict__ b1,
                       const float* __restrict__ w2, const float* __restrict__ u2,
                       const float* __restrict__ b2,
                       const float* __restrict__ dw, const float* __restrict__ db,
                       float* __restrict__ out)           // [B,3]
{
    const int tid = threadIdx.x;
    const int b   = blockIdx.x;

    __shared__ float s_buf[TT];                        // 8 KB input row
    __shared__ __align__(16) _Float16 X1[2 * 176];     // [x(64);h1(100);pad(12)] x2
    __shared__ __align__(16) _Float16 X2[2 * 208];     // [x2(100);p4;h2(100);p4] x2

    for (int i = tid; i < TT; i += 512) s_buf[i] = s[(size_t)b * TT + i];
    if (tid < 2 * 176) X1[tid] = (_Float16)0.0f;
    if (tid < 2 * 208) X2[tid] = (_Float16)0.0f;
    __syncthreads();                                   // (A)

    if (tid < 256) {
        // ================= PRODUCER waves: conv + LSTM1 =================
        const int rt  = tid;
        const int p   = (rt < 200) ? (rt >> 1) : 0;
        const int odd = rt & 1;
        const int cA = p, cB = HH + p, cC = 2 * HH + p, cD = 3 * HH + p;
        const float* W = w1;
        const float* U = u1;
        const int kb = odd ? 88 : 0;                   // K-half base (elements)

        L44(DW)
        L44(LWP)
        const float biA = b1[cA], biB = b1[cB], biC = b1[cC], biD = b1[cD];

        float cv0 = 0.f, cv1 = 0.f, cb0 = 0.f, cv0b = 0.f, cv1b = 0.f, cb0b = 0.f;
        const int f1 = rt - 200;
        if (rt >= 200) {
            cv0 = conv_w[f1]; cv1 = conv_w[FF + f1]; cb0 = conv_b[f1];
            if (f1 < 8) { cv0b = conv_w[56 + f1]; cv1b = conv_w[FF + 56 + f1]; cb0b = conv_b[56 + f1]; }
        }
        if (rt >= 200) {                               // x(0) into slot 0
            X1[f1] = (_Float16)fmaxf(fmaf(s_buf[0], cv0, fmaf(s_buf[1], cv1, cb0)), 0.f);
            if (f1 < 8)
                X1[56 + f1] = (_Float16)fmaxf(fmaf(s_buf[0], cv0b, fmaf(s_buf[1], cv1b, cb0b)), 0.f);
        }
        __syncthreads();                               // (B)

        float c = 0.0f;
        for (int t = 0; t <= TP; ++t) {
            if (t < TP) {
                _Float16* cur = X1 + (t & 1) * 176;
                _Float16* nx1 = X1 + ((t & 1) ^ 1) * 176;
                if (rt < 200) {
                    float zA0 = 0.f, zA1 = 0.f, zB0 = 0.f, zB1 = 0.f;
                    float zC0 = 0.f, zC1 = 0.f, zD0 = 0.f, zD1 = 0.f;
                    const float4* vb = (const float4*)(cur + kb);
                    DOT4(0,0,1,2,3)     DOT4(1,4,5,6,7)     DOT4(2,8,9,10,11)
                    DOT4(3,12,13,14,15) DOT4(4,16,17,18,19) DOT4(5,20,21,22,23)
                    DOT4(6,24,25,26,27) DOT4(7,28,29,30,31) DOT4(8,32,33,34,35)
                    DOT4(9,36,37,38,39) DOT4(10,40,41,42,43)
                    const float zi = pairsum(zA0 + zA1) + biA;
                    const float zf = pairsum(zB0 + zB1) + biB;
                    const float zg = pairsum(zC0 + zC1) + biC;
                    const float zo = pairsum(zD0 + zD1) + biD;
                    const float gi = sig(zi), gf = sig(zf), go = sig(zo);
                    const float gg = fmaxf(zg, 0.f);
                    c = fmaf(gf, c, gi * gg);
                    const float h = go * fmaxf(c, 0.f);
                    if (odd) {
                        const _Float16 hq = (_Float16)h;
                        nx1[FF + p] = hq;                          // h1 for LSTM1(t+1)
                        (X2 + ((t & 1) ^ 1) * 208)[p] = hq;        // x2 for LSTM2
                    }
                } else if (t + 1 < TP) {               // conv x(t+1) into next slot
                    nx1[f1] = (_Float16)fmaxf(fmaf(s_buf[t + 1], cv0, fmaf(s_buf[t + 2], cv1, cb0)), 0.f);
                    if (f1 < 8)
                        nx1[56 + f1] = (_Float16)fmaxf(fmaf(s_buf[t + 1], cv0b, fmaf(s_buf[t + 2], cv1b, cb0b)), 0.f);
                }
            }
            __syncthreads();                           // (C) one per step
        }
    } else {
        // ================= CONSUMER waves: LSTM2 + dense + softmax ==========
        const int rt  = tid - 256;
        const int p   = (rt < 200) ? (rt >> 1) : 0;
        const int odd = rt & 1;
        const int cA = p, cB = HH + p, cC = 2 * HH + p, cD = 3 * HH + p;
        const float* W = w2;
        const float* U = u2;
        const int kb = odd ? 104 : 0;

        L50(DW)
        L50(LWC)
        const float biA = b2[cA], biB = b2[cB], biC = b2[cC], biD = b2[cD];
        __syncthreads();                               // (B)

        float c = 0.0f;
        for (int t = 0; t <= TP; ++t) {
            if (t >= 1 && rt < 200) {                  // consumer step t-1
                _Float16* cur = X2 + (t & 1) * 208;
                float zA0 = 0.f, zA1 = 0.f, zB0 = 0.f, zB1 = 0.f;
                float zC0 = 0.f, zC1 = 0.f, zD0 = 0.f, zD1 = 0.f;
                const float4* vb = (const float4*)(cur + kb);
                DOT4(0,0,1,2,3)     DOT4(1,4,5,6,7)     DOT4(2,8,9,10,11)
                DOT4(3,12,13,14,15) DOT4(4,16,17,18,19) DOT4(5,20,21,22,23)
                DOT4(6,24,25,26,27) DOT4(7,28,29,30,31) DOT4(8,32,33,34,35)
                DOT4(9,36,37,38,39) DOT4(10,40,41,42,43) DOT4(11,44,45,46,47)
                const float2* tb = (const float2*)(cur + kb + 96);
                DOTT(48, 49)
                const float zi = pairsum(zA0 + zA1) + biA;
                const float zf = pairsum(zB0 + zB1) + biB;
                const float zg = pairsum(zC0 + zC1) + biC;
                const float zo = pairsum(zD0 + zD1) + biD;
                const float gi = sig(zi), gf = sig(zf), go = sig(zo);
                const float gg = fmaxf(zg, 0.f);
                c = fmaf(gf, c, gi * gg);
                const float h = go * fmaxf(c, 0.f);
                if (odd) X2[((t & 1) ^ 1) * 208 + 104 + p] = (_Float16)h;
            }
            __syncthreads();                           // (C) one per step
        }

        // final h2(TP-1) was written at iter TP into slot ((TP&1)^1)=0
        if (rt == 0) {
            float l[3];
#pragma unroll
            for (int a = 0; a < 3; ++a) {
                float acc = db[a];
                for (int j = 0; j < HH; ++j)
                    acc = fmaf((float)X2[104 + j], dw[j * 3 + a], acc);
                l[a] = acc;
            }
            const float m = fmaxf(l[0], fmaxf(l[1], l[2]));
            const float e0 = __expf(l[0] - m), e1 = __expf(l[1] - m), e2 = __expf(l[2] - m);
            const float inv = 1.0f / (e0 + e1 + e2);
            out[b * 3 + 0] = e0 * inv;
            out[b * 3 + 1] = e1 * inv;
            out[b * 3 + 2] = e2 * inv;
        }
    }
}

// ---------------- launch ----------------------------------------------------
extern "C" void kernel_launch(void* const* d_in, const int* in_sizes, int n_in,
                              void* d_out, int out_size, void* d_ws, size_t ws_size,
                              hipStream_t stream) {
    const float* s      = (const float*)d_in[0];
    const float* conv_w = (const float*)d_in[1];
    const float* conv_b = (const float*)d_in[2];
    const float* w1     = (const float*)d_in[3];
    const float* u1     = (const float*)d_in[4];
    const float* b1     = (const float*)d_in[5];
    const float* w2     = (const float*)d_in[6];
    const float* u2     = (const float*)d_in[7];
    const float* b2     = (const float*)d_in[8];
    const float* dw     = (const float*)d_in[9];
    const float* db     = (const float*)d_in[10];

    fused_lstm_kernel<<<BB, 512, 0, stream>>>(
        s, conv_w, conv_b, w1, u1, b1, w2, u2, b2, dw, db, (float*)d_out);
}